// Round 11
// baseline (245.615 us; speedup 1.0000x reference)
//
#include <hip/hip_runtime.h>

// R16: single-variable change vs R15 — legacy mfma_f32_16x16x16f16 replaced
// by gfx950-NATIVE __builtin_amdgcn_mfma_f32_16x16x32_f16, half-K zero-padded.
// Evidence: measured VALUBusy ~3x hand-counted VALU (R8) + occupancy collapse
// at VGPR_Count=80 (R11) -> legacy-shape accumulators shuttle through AGPRs
// (v_accvgpr_write/read around every MFMA + hidden AGPR allocation). Native
// shapes hold C/D in the unified file in-place (m97 asm evidence).
// Mapping: A and B both put real data in j-slots 0..3 and exact zeros in
// j=4..7. A/B share the same (lane,j)->k map, so real products pair exactly
// as in the legacy shape; the extra 16 products are exact +0 contributions.
// C/D layout of 16x16x32 is the HW-verified col=lane&15, row=4*(lane>>4)+i —
// IDENTICAL to legacy — so relu-pack, quad-select B-zeroing, L3 row-shifted
// variants, C-chaining, and full-wave stores are all byte-for-byte R15.
//   - L1: B tile s nonzero only in quad s, j=0..2 = {x0,x1,x2}; a1 broadcast
//     {w0,w1,w2,0,0,0,0,0}.
//   - L2: B = h[4q+j] at j=0..3; A2 = W2[m][4q+j] at j=0..3, zeros j>=4.
//   - L3: variant s holds W3 rows 4s..4s+2 (C-chained, untouched rows +0).
// Structure unchanged from R15: NG=12 straight-line fast path, 2-deep
// prefetch, full-wave 256B loads/stores, wave-uniform group guards (64 | N),
// XCD swizzle. launch_bounds(256,5): +12 VGPR for doubled A operands.
//
// Frag layouts (16x16x32 native, gfx950):
//   A[m][*]: lane m=lane&15, 8 halves; j<4 slots carry the legacy 4q+j data
//   B[*][n]: lane n=lane&15, 8 halves; same j<->k map as A
//   C/D:     lane n=lane&15, row = 4*(lane>>4) + i (4 fp32)  [verified]

#define MFMA32(a, b, c) __builtin_amdgcn_mfma_f32_16x16x32_f16((a), (b), (c), 0, 0, 0)

#define TPG 4                        // tiles per group (64 points)
#define NG 12                        // groups per wave
#define WAVES_PER_BLOCK 4
#define PTS_PER_WAVE (NG * 64)                           // 768
#define PTS_PER_BLOCK (PTS_PER_WAVE * WAVES_PER_BLOCK)   // 3072

typedef __fp16 pk16x2 __attribute__((ext_vector_type(2)));   // cvt_pkrtz return
typedef _Float16 half8_t __attribute__((ext_vector_type(8)));
typedef float float4_t __attribute__((ext_vector_type(4)));

union H2I { pk16x2 h; int i; };
union Frag8 { half8_t v; int i[4]; };

__device__ __forceinline__ int pkrtz(float a, float b) {
    H2I u; u.h = __builtin_amdgcn_cvt_pkrtz(a, b); return u.i;
}

// relu on a packed f16 pair: cvt_pkrtz then v_pk_max_f16 with +0 (R11-proven)
__device__ __forceinline__ int pk_relu_pack(float a, float b) {
    H2I u; u.h = __builtin_amdgcn_cvt_pkrtz(a, b);
    const pk16x2 z = {(__fp16)0.f, (__fp16)0.f};
    u.h = __builtin_elementwise_max(u.h, z);
    return u.i;
}

__global__ __launch_bounds__(256, 5) void fields_r16_kernel(
    const float* __restrict__ x,
    const float* __restrict__ W1, const float* __restrict__ b1,
    const float* __restrict__ W2, const float* __restrict__ b2,
    const float* __restrict__ W3, const float* __restrict__ b3,
    float* __restrict__ out, int N)
{
    const int lane = threadIdx.x & 63;
    const int wave = threadIdx.x >> 6;
    const int q    = lane >> 4;        // quad 0..3
    const int n16  = lane & 15;        // row m for A-frags

    // ---- XCD-swizzled decode: chunk c = 8a + r runs on XCD r = c%8 ----
    const int bid = blockIdx.x;
    const int r   = bid & 7;
    const int d   = (bid >> 3) & 15;   // field
    const int a   = bid >> 7;
    const int chunk  = a * 8 + r;
    const int chunks = (N + PTS_PER_BLOCK - 1) / PTS_PER_BLOCK;
    if (chunk >= chunks) return;       // pad blocks (grid rounded to *8)

    const int base = chunk * PTS_PER_BLOCK + wave * PTS_PER_WAVE;
    const bool isq[TPG] = { q == 0, q == 1, q == 2, q == 3 };

    // ---- field d's weights -> registers, native frags (j>=4 zero) ----
    Frag8 a1, a2, a3v[TPG];
    {
        const float* w1 = W1 + (d * 16 + n16) * 3;
        a1.v = (half8_t){(_Float16)w1[0], (_Float16)w1[1], (_Float16)w1[2],
                         (_Float16)0.f, (_Float16)0.f, (_Float16)0.f,
                         (_Float16)0.f, (_Float16)0.f};    // quad-broadcast
        const float4_t w2 = *(const float4_t*)(W2 + (d * 16 + n16) * 16 + q * 4);
        a2.v = (half8_t){(_Float16)w2.x, (_Float16)w2.y, (_Float16)w2.z,
                         (_Float16)w2.w, (_Float16)0.f, (_Float16)0.f,
                         (_Float16)0.f, (_Float16)0.f};
#pragma unroll
        for (int s = 0; s < TPG; ++s) {
            const int m = n16 - 4 * s;
            if (m >= 0 && m < 3) {
                const float4_t w3 = *(const float4_t*)(W3 + (d * 3 + m) * 16 + q * 4);
                a3v[s].v = (half8_t){(_Float16)w3.x, (_Float16)w3.y,
                                     (_Float16)w3.z, (_Float16)w3.w,
                                     (_Float16)0.f, (_Float16)0.f,
                                     (_Float16)0.f, (_Float16)0.f};
            } else {
                a3v[s].i[0] = 0; a3v[s].i[1] = 0;
                a3v[s].i[2] = 0; a3v[s].i[3] = 0;
            }
        }
    }
    const float4_t b1v = *(const float4_t*)(b1 + d * 16 + q * 4);
    const float4_t b2v = *(const float4_t*)(b2 + d * 16 + q * 4);
    const float4_t b3r = (float4_t){b3[d * 3 + 0], b3[d * 3 + 1],
                                    b3[d * 3 + 2], 0.f};

    // ---- UNIFORM base pointers (SGPR); per-lane index = lane + 64g ----
    const float* xp0 = x + base;
    const float* xp1 = xp0 + N;
    const float* xp2 = xp1 + N;
    float* op0 = out + (size_t)(d * 3 + 0) * N + base;
    float* op1 = out + (size_t)(d * 3 + 1) * N + base;
    float* op2 = out + (size_t)(d * 3 + 2) * N + base;

    if (base + PTS_PER_WAVE <= N) {
        // ===== fast path: straight-line, no control flow between groups ====
        float rb[2][3];                    // 2-deep prefetch, static indices
        rb[0][0] = xp0[lane];      rb[0][1] = xp1[lane];      rb[0][2] = xp2[lane];
        rb[1][0] = xp0[lane + 64]; rb[1][1] = xp1[lane + 64]; rb[1][2] = xp2[lane + 64];

#pragma unroll
        for (int g = 0; g < NG; ++g) {
            const int b = g & 1;           // compile-time after unroll

            const int p01 = pkrtz(rb[b][0], rb[b][1]);
            const int p2  = pkrtz(rb[b][2], 0.f);

            if (g + 2 < NG) {              // prefetch group g+2
                rb[b][0] = xp0[lane + (g + 2) * 64];
                rb[b][1] = xp1[lane + (g + 2) * 64];
                rb[b][2] = xp2[lane + (g + 2) * 64];
            }

            Frag8 xf[TPG];
#pragma unroll
            for (int s = 0; s < TPG; ++s) {
                xf[s].i[0] = isq[s] ? p01 : 0;   // B nonzero only in quad s
                xf[s].i[1] = isq[s] ? p2  : 0;
                xf[s].i[2] = 0;
                xf[s].i[3] = 0;
            }

            float4_t acc[TPG];
#pragma unroll
            for (int s = 0; s < TPG; ++s) acc[s] = MFMA32(a1.v, xf[s].v, b1v);
            Frag8 hf[TPG];
#pragma unroll
            for (int s = 0; s < TPG; ++s) {
                hf[s].i[0] = pk_relu_pack(acc[s].x, acc[s].y);
                hf[s].i[1] = pk_relu_pack(acc[s].z, acc[s].w);
                hf[s].i[2] = 0;
                hf[s].i[3] = 0;
            }
#pragma unroll
            for (int s = 0; s < TPG; ++s) acc[s] = MFMA32(a2.v, hf[s].v, b2v);
#pragma unroll
            for (int s = 0; s < TPG; ++s) {
                hf[s].i[0] = pk_relu_pack(acc[s].x, acc[s].y);
                hf[s].i[1] = pk_relu_pack(acc[s].z, acc[s].w);
            }
            float4_t o = b3r;              // C-chained L3 variants (exact)
#pragma unroll
            for (int s = 0; s < TPG; ++s) o = MFMA32(a3v[s].v, hf[s].v, o);

            op0[lane + g * 64] = o.x;      // full-wave 256B stores
            op1[lane + g * 64] = o.y;
            op2[lane + g * 64] = o.z;
        }
    } else {
        // ===== tail path (few waves chip-wide): guarded group loop ====
        int nvalid = (N > base) ? (N - base) / 64 : 0;   // 64 | N
        if (nvalid > NG) nvalid = NG;

        float rb[2][3];
        if (0 < nvalid) {
            rb[0][0] = xp0[lane]; rb[0][1] = xp1[lane]; rb[0][2] = xp2[lane];
        }
        if (1 < nvalid) {
            rb[1][0] = xp0[lane + 64]; rb[1][1] = xp1[lane + 64]; rb[1][2] = xp2[lane + 64];
        }

#pragma unroll
        for (int g = 0; g < NG; ++g) {
            if (g >= nvalid) break;        // wave-uniform scalar branch
            const int b = g & 1;

            const int p01 = pkrtz(rb[b][0], rb[b][1]);
            const int p2  = pkrtz(rb[b][2], 0.f);

            if (g + 2 < nvalid) {
                rb[b][0] = xp0[lane + (g + 2) * 64];
                rb[b][1] = xp1[lane + (g + 2) * 64];
                rb[b][2] = xp2[lane + (g + 2) * 64];
            }

            Frag8 xf[TPG];
#pragma unroll
            for (int s = 0; s < TPG; ++s) {
                xf[s].i[0] = isq[s] ? p01 : 0;
                xf[s].i[1] = isq[s] ? p2  : 0;
                xf[s].i[2] = 0;
                xf[s].i[3] = 0;
            }

            float4_t acc[TPG];
#pragma unroll
            for (int s = 0; s < TPG; ++s) acc[s] = MFMA32(a1.v, xf[s].v, b1v);
            Frag8 hf[TPG];
#pragma unroll
            for (int s = 0; s < TPG; ++s) {
                hf[s].i[0] = pk_relu_pack(acc[s].x, acc[s].y);
                hf[s].i[1] = pk_relu_pack(acc[s].z, acc[s].w);
                hf[s].i[2] = 0;
                hf[s].i[3] = 0;
            }
#pragma unroll
            for (int s = 0; s < TPG; ++s) acc[s] = MFMA32(a2.v, hf[s].v, b2v);
#pragma unroll
            for (int s = 0; s < TPG; ++s) {
                hf[s].i[0] = pk_relu_pack(acc[s].x, acc[s].y);
                hf[s].i[1] = pk_relu_pack(acc[s].z, acc[s].w);
            }
            float4_t o = b3r;
#pragma unroll
            for (int s = 0; s < TPG; ++s) o = MFMA32(a3v[s].v, hf[s].v, o);

            op0[lane + g * 64] = o.x;
            op1[lane + g * 64] = o.y;
            op2[lane + g * 64] = o.z;
        }
    }
}

extern "C" void kernel_launch(void* const* d_in, const int* in_sizes, int n_in,
                              void* d_out, int out_size, void* d_ws, size_t ws_size,
                              hipStream_t stream) {
    const float* x  = (const float*)d_in[0];
    const float* W1 = (const float*)d_in[1];
    const float* b1 = (const float*)d_in[2];
    const float* W2 = (const float*)d_in[3];
    const float* b2 = (const float*)d_in[4];
    const float* W3 = (const float*)d_in[5];
    const float* b3 = (const float*)d_in[6];
    float* out = (float*)d_out;

    const int N = in_sizes[0] / 3;  // x is [1,3,N]
    const int chunks = (N + PTS_PER_BLOCK - 1) / PTS_PER_BLOCK;   // 326
    const int a_max  = (chunks + 7) / 8;                          // 41
    const int grid   = 8 * 16 * a_max;                            // 5248
    fields_r16_kernel<<<grid, 256, 0, stream>>>(x, W1, b1, W2, b2, W3, b3, out, N);
}

// Round 12
// 231.486 us; speedup vs baseline: 1.0610x; 1.0610x over previous
//
#include <hip/hip_runtime.h>

// R17: hot-loop VALU diet — L1 masking flipped from B-side to A-side.
// R16 (native 16x16x32, zero-padded) regressed 232->245: operand bloat +
// zeroing moves outweighed everything; reverted. R15 base, one change:
//   - OLD: per group build 4 quad-gated B-frags (8 cndmask) against one
//     broadcast A1.
//   - NEW: ONE un-gated B-frag (lane l carries its own point's {x0,x1,x2,0})
//     against 4 precomputed A1 VARIANTS (variant s nonzero only in quad-s
//     lanes; built once per wave). Layout-agnostic exactness: A and B share
//     the same (q,j)->k map, so quad-s A pairs with quad-s B, slot j with
//     slot j -> products w_j*x_j(16s+n) at identical k positions as R15;
//     everything else is exact 0. Bitwise-identical output.
//   - Saves 8 VALU/group (96/wave); register footprint net-zero
//     (+6 a1v, -6 xf). Everything else byte-for-byte R15: NG=12
//     straight-line, 2-deep prefetch, full-wave 256B loads/stores, L3
//     row-shifted variants C-chained, pk_relu_pack, launch_bounds(256,6),
//     XCD swizzle, wave-uniform group guards (64 | N).
//
// Frag layouts (16x16x16, CDNA family):
//   A[m][k]: lane m=lane&15, k = 4*(lane>>4) + j   (4 f16, 2 VGPRs)
//   B[k][n]: lane n=lane&15, k = 4*(lane>>4) + j
//   C/D:     lane n=lane&15, row = 4*(lane>>4) + i (4 fp32)

#define MFMA16(a, b, c) __builtin_amdgcn_mfma_f32_16x16x16f16((a), (b), (c), 0, 0, 0)

#define TPG 4                        // tiles per group (64 points)
#define NG 12                        // groups per wave
#define WAVES_PER_BLOCK 4
#define PTS_PER_WAVE (NG * 64)                           // 768
#define PTS_PER_BLOCK (PTS_PER_WAVE * WAVES_PER_BLOCK)   // 3072

typedef __fp16 pk16x2 __attribute__((ext_vector_type(2)));   // cvt_pkrtz return
typedef _Float16 half4_t __attribute__((ext_vector_type(4)));
typedef float float4_t __attribute__((ext_vector_type(4)));

union H2I { pk16x2 h; int i; };
union Frag { half4_t v; int i[2]; };

__device__ __forceinline__ int pkrtz(float a, float b) {
    H2I u; u.h = __builtin_amdgcn_cvt_pkrtz(a, b); return u.i;
}

// relu on a packed f16 pair: cvt_pkrtz then v_pk_max_f16 with +0 (R11-proven)
__device__ __forceinline__ int pk_relu_pack(float a, float b) {
    H2I u; u.h = __builtin_amdgcn_cvt_pkrtz(a, b);
    const pk16x2 z = {(__fp16)0.f, (__fp16)0.f};
    u.h = __builtin_elementwise_max(u.h, z);
    return u.i;
}

__global__ __launch_bounds__(256, 6) void fields_r17_kernel(
    const float* __restrict__ x,
    const float* __restrict__ W1, const float* __restrict__ b1,
    const float* __restrict__ W2, const float* __restrict__ b2,
    const float* __restrict__ W3, const float* __restrict__ b3,
    float* __restrict__ out, int N)
{
    const int lane = threadIdx.x & 63;
    const int wave = threadIdx.x >> 6;
    const int q    = lane >> 4;        // quad 0..3
    const int n16  = lane & 15;        // row m for A-frags

    // ---- XCD-swizzled decode: chunk c = 8a + r runs on XCD r = c%8 ----
    const int bid = blockIdx.x;
    const int r   = bid & 7;
    const int d   = (bid >> 3) & 15;   // field
    const int a   = bid >> 7;
    const int chunk  = a * 8 + r;
    const int chunks = (N + PTS_PER_BLOCK - 1) / PTS_PER_BLOCK;
    if (chunk >= chunks) return;       // pad blocks (grid rounded to *8)

    const int base = chunk * PTS_PER_BLOCK + wave * PTS_PER_WAVE;

    // ---- field d's weights -> registers, frag-ready ----
    // a1v[s]: L1 A-variant, nonzero only for quad-s lanes ({w0,w1,w2,0}).
    Frag a1v[TPG], a2, a3v[TPG];
    {
        const float* w1 = W1 + (d * 16 + n16) * 3;
        const half4_t w1h = (half4_t){(_Float16)w1[0], (_Float16)w1[1],
                                      (_Float16)w1[2], (_Float16)0.f};
        Frag zf; zf.i[0] = 0; zf.i[1] = 0;
#pragma unroll
        for (int s = 0; s < TPG; ++s)
            a1v[s].v = (q == s) ? w1h : zf.v;      // built once per wave

        const float4_t w2 = *(const float4_t*)(W2 + (d * 16 + n16) * 16 + q * 4);
        a2.v = (half4_t){(_Float16)w2.x, (_Float16)w2.y, (_Float16)w2.z,
                         (_Float16)w2.w};
#pragma unroll
        for (int s = 0; s < TPG; ++s) {            // L3 row-shifted variants
            const int m = n16 - 4 * s;
            if (m >= 0 && m < 3) {
                const float4_t w3 = *(const float4_t*)(W3 + (d * 3 + m) * 16 + q * 4);
                a3v[s].v = (half4_t){(_Float16)w3.x, (_Float16)w3.y,
                                     (_Float16)w3.z, (_Float16)w3.w};
            } else {
                a3v[s].i[0] = 0; a3v[s].i[1] = 0;
            }
        }
    }
    const float4_t b1v = *(const float4_t*)(b1 + d * 16 + q * 4);
    const float4_t b2v = *(const float4_t*)(b2 + d * 16 + q * 4);
    const float4_t b3r = (float4_t){b3[d * 3 + 0], b3[d * 3 + 1],
                                    b3[d * 3 + 2], 0.f};

    // ---- UNIFORM base pointers (SGPR); per-lane index = lane + 64g ----
    const float* xp0 = x + base;
    const float* xp1 = xp0 + N;
    const float* xp2 = xp1 + N;
    float* op0 = out + (size_t)(d * 3 + 0) * N + base;
    float* op1 = out + (size_t)(d * 3 + 1) * N + base;
    float* op2 = out + (size_t)(d * 3 + 2) * N + base;

    if (base + PTS_PER_WAVE <= N) {
        // ===== fast path: straight-line, no control flow between groups ====
        float rb[2][3];                    // 2-deep prefetch, static indices
        rb[0][0] = xp0[lane];      rb[0][1] = xp1[lane];      rb[0][2] = xp2[lane];
        rb[1][0] = xp0[lane + 64]; rb[1][1] = xp1[lane + 64]; rb[1][2] = xp2[lane + 64];

#pragma unroll
        for (int g = 0; g < NG; ++g) {
            const int b = g & 1;           // compile-time after unroll

            // ONE un-gated B-frag: lane l = point g*64+l, slots {x0,x1,x2,0}
            Frag xf;
            xf.i[0] = pkrtz(rb[b][0], rb[b][1]);
            xf.i[1] = pkrtz(rb[b][2], 0.f);

            if (g + 2 < NG) {              // prefetch group g+2
                rb[b][0] = xp0[lane + (g + 2) * 64];
                rb[b][1] = xp1[lane + (g + 2) * 64];
                rb[b][2] = xp2[lane + (g + 2) * 64];
            }

            // layer 1: 4 MFMAs sharing one B, gated by the A1 variants
            float4_t acc[TPG];
#pragma unroll
            for (int s = 0; s < TPG; ++s) acc[s] = MFMA16(a1v[s].v, xf.v, b1v);
            Frag hf[TPG];
#pragma unroll
            for (int s = 0; s < TPG; ++s) {
                hf[s].i[0] = pk_relu_pack(acc[s].x, acc[s].y);
                hf[s].i[1] = pk_relu_pack(acc[s].z, acc[s].w);
            }
            // layer 2
#pragma unroll
            for (int s = 0; s < TPG; ++s) acc[s] = MFMA16(a2.v, hf[s].v, b2v);
#pragma unroll
            for (int s = 0; s < TPG; ++s) {
                hf[s].i[0] = pk_relu_pack(acc[s].x, acc[s].y);
                hf[s].i[1] = pk_relu_pack(acc[s].z, acc[s].w);
            }
            // layer 3: C-chained row-shifted variants (untouched rows +0)
            float4_t o = b3r;
#pragma unroll
            for (int s = 0; s < TPG; ++s) o = MFMA16(a3v[s].v, hf[s].v, o);

            op0[lane + g * 64] = o.x;      // full-wave 256B stores
            op1[lane + g * 64] = o.y;
            op2[lane + g * 64] = o.z;
        }
    } else {
        // ===== tail path (few waves chip-wide): guarded group loop ====
        int nvalid = (N > base) ? (N - base) / 64 : 0;   // 64 | N
        if (nvalid > NG) nvalid = NG;

        float rb[2][3];
        if (0 < nvalid) {
            rb[0][0] = xp0[lane]; rb[0][1] = xp1[lane]; rb[0][2] = xp2[lane];
        }
        if (1 < nvalid) {
            rb[1][0] = xp0[lane + 64]; rb[1][1] = xp1[lane + 64]; rb[1][2] = xp2[lane + 64];
        }

#pragma unroll
        for (int g = 0; g < NG; ++g) {
            if (g >= nvalid) break;        // wave-uniform scalar branch
            const int b = g & 1;

            Frag xf;
            xf.i[0] = pkrtz(rb[b][0], rb[b][1]);
            xf.i[1] = pkrtz(rb[b][2], 0.f);

            if (g + 2 < nvalid) {
                rb[b][0] = xp0[lane + (g + 2) * 64];
                rb[b][1] = xp1[lane + (g + 2) * 64];
                rb[b][2] = xp2[lane + (g + 2) * 64];
            }

            float4_t acc[TPG];
#pragma unroll
            for (int s = 0; s < TPG; ++s) acc[s] = MFMA16(a1v[s].v, xf.v, b1v);
            Frag hf[TPG];
#pragma unroll
            for (int s = 0; s < TPG; ++s) {
                hf[s].i[0] = pk_relu_pack(acc[s].x, acc[s].y);
                hf[s].i[1] = pk_relu_pack(acc[s].z, acc[s].w);
            }
#pragma unroll
            for (int s = 0; s < TPG; ++s) acc[s] = MFMA16(a2.v, hf[s].v, b2v);
#pragma unroll
            for (int s = 0; s < TPG; ++s) {
                hf[s].i[0] = pk_relu_pack(acc[s].x, acc[s].y);
                hf[s].i[1] = pk_relu_pack(acc[s].z, acc[s].w);
            }
            float4_t o = b3r;
#pragma unroll
            for (int s = 0; s < TPG; ++s) o = MFMA16(a3v[s].v, hf[s].v, o);

            op0[lane + g * 64] = o.x;
            op1[lane + g * 64] = o.y;
            op2[lane + g * 64] = o.z;
        }
    }
}

extern "C" void kernel_launch(void* const* d_in, const int* in_sizes, int n_in,
                              void* d_out, int out_size, void* d_ws, size_t ws_size,
                              hipStream_t stream) {
    const float* x  = (const float*)d_in[0];
    const float* W1 = (const float*)d_in[1];
    const float* b1 = (const float*)d_in[2];
    const float* W2 = (const float*)d_in[3];
    const float* b2 = (const float*)d_in[4];
    const float* W3 = (const float*)d_in[5];
    const float* b3 = (const float*)d_in[6];
    float* out = (float*)d_out;

    const int N = in_sizes[0] / 3;  // x is [1,3,N]
    const int chunks = (N + PTS_PER_BLOCK - 1) / PTS_PER_BLOCK;   // 326
    const int a_max  = (chunks + 7) / 8;                          // 41
    const int grid   = 8 * 16 * a_max;                            // 5248
    fields_r17_kernel<<<grid, 256, 0, stream>>>(x, W1, b1, W2, b2, W3, b3, out, N);
}